// Round 9
// baseline (144.916 us; speedup 1.0000x reference)
//
#include <hip/hip_runtime.h>

// Trilinear interpolation, grid (128,128,128,8) f32, 2M random points.
// Round 9: single-variable A/B vs r8 -- NON-TEMPORAL output stores.
// r6/r7/r8 pinned the interp at ~84-93us tracking "random 64B lines touched"
// (~24G lines/s) independent of payload/occupancy. Hypothesis: L2 write-
// allocate/retention of 2M never-re-read lines is the wall; nt stores stream
// sectors out without L2 line churn. Null result => TCC tag wall, go hybrid.

#define GS    128
#define NBX   32                    // x-slabs (pass 1)
#define NB2   4096                  // fine buckets (x/4,y/4,z/32)
#define CAP1  65536                 // recs1 region per slab  (mean 62500)
#define CAP2  704                   // recs2 region per fine bucket (mean 488)
#define K_PTS 1024                  // points per sort block
#define HCELLS (5 * 5 * 33)         // 825 halo cells

typedef float __attribute__((ext_vector_type(4))) f32x4;

__device__ __forceinline__ void cell_of(
    float cx, float cy, float cz,
    float b0x, float b0y, float b0z,
    float sx, float sy, float sz,
    int& x0, int& y0, int& z0)
{
    float nx = fminf(fmaxf((cx - b0x) / sx, 0.0f), 1.0f);
    float ny = fminf(fmaxf((cy - b0y) / sy, 0.0f), 1.0f);
    float nz = fminf(fmaxf((cz - b0z) / sz, 0.0f), 1.0f);
    x0 = (int)(nx * (float)(GS - 1));
    y0 = (int)(ny * (float)(GS - 1));
    z0 = (int)(nz * (float)(GS - 1));
}

// ---------------- K0: init cursors to region starts ----------------
__global__ __launch_bounds__(256) void k_init(
    unsigned* __restrict__ cursor32, unsigned* __restrict__ cursor4096)
{
    int i = blockIdx.x * 256 + threadIdx.x;
    if (i < NBX) cursor32[i] = (unsigned)i * CAP1;
    if (i < NB2) cursor4096[i] = (unsigned)i * CAP2;
}

// ---------------- K1: pass-1 scatter by x-slab (burst ~32) ----------------
__global__ __launch_bounds__(256) void k_scatter1(
    const float* __restrict__ coords,
    const float* __restrict__ bbox_min,
    const float* __restrict__ bbox_max,
    unsigned* __restrict__ cursor32,
    float4* __restrict__ recs1, int n)
{
    __shared__ float4 srec[K_PTS];
    __shared__ unsigned char sbkt[K_PTS];
    __shared__ unsigned cnt[NBX], lbase[NBX], gbase[NBX];

    int t = threadIdx.x;
    if (t < NBX) cnt[t] = 0;
    __syncthreads();

    float b0x = bbox_min[0];
    float sx  = fmaxf(bbox_max[0] - b0x, 1e-6f);
    long long base = (long long)blockIdx.x * K_PTS;
    int m = (int)min((long long)K_PTS, (long long)n - base);

    float cx[4], cy[4], cz[4];
    int bb[4]; unsigned rr[4];
    int j0 = 4 * t;
    if (j0 + 3 < m) {
        const float4* c4 = (const float4*)coords + (size_t)blockIdx.x * 768 + 3 * t;
        float4 f0 = c4[0], f1 = c4[1], f2 = c4[2];
        cx[0] = f0.x; cy[0] = f0.y; cz[0] = f0.z;
        cx[1] = f0.w; cy[1] = f1.x; cz[1] = f1.y;
        cx[2] = f1.z; cy[2] = f1.w; cz[2] = f2.x;
        cx[3] = f2.y; cy[3] = f2.z; cz[3] = f2.w;
    } else {
#pragma unroll
        for (int p = 0; p < 4; ++p) {
            int j = j0 + p;
            if (j < m) {
                long long i = base + j;
                cx[p] = coords[3 * i]; cy[p] = coords[3 * i + 1]; cz[p] = coords[3 * i + 2];
            }
        }
    }
#pragma unroll
    for (int p = 0; p < 4; ++p) {
        int j = j0 + p;
        if (j < m) {
            float nx = fminf(fmaxf((cx[p] - b0x) / sx, 0.0f), 1.0f);
            bb[p] = ((int)(nx * (float)(GS - 1))) >> 2;
            rr[p] = atomicAdd(&cnt[bb[p]], 1u);
        }
    }
    __syncthreads();

    if (t == 0) {
        unsigned acc = 0;
        for (int j = 0; j < NBX; ++j) { lbase[j] = acc; acc += cnt[j]; }
    }
    if (t < NBX && cnt[t]) gbase[t] = atomicAdd(&cursor32[t], cnt[t]);
    __syncthreads();

#pragma unroll
    for (int p = 0; p < 4; ++p) {
        int j = j0 + p;
        if (j < m) {
            unsigned slot = lbase[bb[p]] + rr[p];
            float4 r; r.x = cx[p]; r.y = cy[p]; r.z = cz[p];
            r.w = __uint_as_float((unsigned)(base + j));
            srec[slot] = r;
            sbkt[slot] = (unsigned char)bb[p];
        }
    }
    __syncthreads();

#pragma unroll
    for (int k = 0; k < 4; ++k) {
        int j = k * 256 + t;
        if (j < m) {
            int b = sbkt[j];
            unsigned d = gbase[b] + (unsigned)j - lbase[b];
            if (d < (unsigned)(b + 1) * CAP1) recs1[d] = srec[j];
        }
    }
}

// ------- K2: pass-2 scatter within slab -> 128 fine buckets ----------------
__global__ __launch_bounds__(256) void k_scatter2(
    const float4* __restrict__ recs1,
    const float* __restrict__ bbox_min,
    const float* __restrict__ bbox_max,
    const unsigned* __restrict__ cursor32_final,
    unsigned* __restrict__ cursor4096,
    float4* __restrict__ recs2)
{
    __shared__ float4 srec[K_PTS];
    __shared__ unsigned char sbkt[K_PTS];
    __shared__ unsigned cnt[128], lbase[128], gbase[128];

    int s = blockIdx.x >> 6;        // slab
    int c = blockIdx.x & 63;        // chunk within slab region
    unsigned fill = cursor32_final[s] - (unsigned)s * CAP1;
    if (fill > CAP1) fill = CAP1;
    unsigned off = (unsigned)c * 1024;
    if (off >= fill) return;
    int m = (int)min(1024u, fill - off);

    int t = threadIdx.x;
    if (t < 128) cnt[t] = 0;
    __syncthreads();

    float b0x = bbox_min[0], b0y = bbox_min[1], b0z = bbox_min[2];
    float sx = fmaxf(bbox_max[0] - b0x, 1e-6f);
    float sy = fmaxf(bbox_max[1] - b0y, 1e-6f);
    float sz = fmaxf(bbox_max[2] - b0z, 1e-6f);
    long long base = (long long)s * CAP1 + off;

    float4 rc[4]; int bb[4]; unsigned rr[4];
#pragma unroll
    for (int k = 0; k < 4; ++k) {
        int j = k * 256 + t;
        if (j < m) {
            rc[k] = recs1[base + j];
            int x0, y0, z0;
            cell_of(rc[k].x, rc[k].y, rc[k].z, b0x, b0y, b0z, sx, sy, sz, x0, y0, z0);
            bb[k] = ((y0 >> 2) << 2) | (z0 >> 5);   // local fine bucket 0..127
            rr[k] = atomicAdd(&cnt[bb[k]], 1u);
        }
    }
    __syncthreads();

    if (t == 0) {
        unsigned acc = 0;
        for (int j = 0; j < 128; ++j) { lbase[j] = acc; acc += cnt[j]; }
    }
    if (t < 128 && cnt[t]) gbase[t] = atomicAdd(&cursor4096[s * 128 + t], cnt[t]);
    __syncthreads();

#pragma unroll
    for (int k = 0; k < 4; ++k) {
        int j = k * 256 + t;
        if (j < m) {
            unsigned slot = lbase[bb[k]] + rr[k];
            srec[slot] = rc[k];
            sbkt[slot] = (unsigned char)bb[k];
        }
    }
    __syncthreads();

#pragma unroll
    for (int k = 0; k < 4; ++k) {
        int j = k * 256 + t;
        if (j < m) {
            int lb = sbkt[j];
            unsigned g = (unsigned)s * 128 + lb;
            unsigned d = gbase[lb] + (unsigned)j - lbase[lb];
            if (d < (g + 1) * CAP2) recs2[d] = srec[j];
        }
    }
}

// ------- K3: LDS-staged interp, recs in LDS, NON-TEMPORAL stores -----------
__global__ __launch_bounds__(512) void k_interp_staged(
    const float4* __restrict__ recs2,
    const unsigned* __restrict__ cursor4096_final,
    const float* __restrict__ grid,
    const float* __restrict__ bbox_min,
    const float* __restrict__ bbox_max,
    float4* __restrict__ out4)
{
    __shared__ float4 tile[HCELLS * 2];   // 26.4 KB
    __shared__ float4 srec[CAP2];         // 11.3 KB

    // XCD-chunked: each XCD gets 512 contiguous buckets (4 full x-slabs)
    int ob = blockIdx.x;
    int b  = (ob & 7) * 512 + (ob >> 3);

    unsigned s0 = (unsigned)b * CAP2;
    unsigned e  = cursor4096_final[b];
    unsigned cap_end = s0 + CAP2;
    if (e > cap_end) e = cap_end;
    if (e <= s0) return;
    int cnt = (int)(e - s0);

    int xs = b >> 7, ys = (b >> 2) & 31, zq = b & 3;
    int t = threadIdx.x;

    // stage bucket records (coalesced)
    for (int k = t; k < cnt; k += 512) srec[k] = recs2[s0 + k];

    // stage halo (5x5x33 cells x 32B), coalesced along z
    const float4* g4 = (const float4*)grid;
    for (int k = t; k < HCELLS * 2; k += 512) {
        int c  = k >> 1, half = k & 1;
        int lx = c / 165;
        int r2 = c - lx * 165;
        int ly = r2 / 33;
        int lz = r2 - ly * 33;
        int gx = min(xs * 4 + lx, GS - 1);
        int gy = min(ys * 4 + ly, GS - 1);
        int gz = min(zq * 32 + lz, GS - 1);
        tile[k] = g4[(((gx * GS) + gy) * GS + gz) * 2 + half];
    }
    __syncthreads();

    const float eps = 1e-6f;
    float b0x = bbox_min[0], b0y = bbox_min[1], b0z = bbox_min[2];
    float sx = fmaxf(bbox_max[0] - b0x, eps);
    float sy = fmaxf(bbox_max[1] - b0y, eps);
    float sz = fmaxf(bbox_max[2] - b0z, eps);

    int pair = t >> 1, half = t & 1;   // 256 points per iteration

    for (int cb = 0; cb < cnt; cb += 256) {
        int j = cb + pair;
        if (j >= cnt) continue;
        float4 rec = srec[j];           // LDS broadcast to pair lanes
        unsigned orig = __float_as_uint(rec.w);

        float nx = fminf(fmaxf((rec.x - b0x) / sx, 0.0f), 1.0f);
        float ny = fminf(fmaxf((rec.y - b0y) / sy, 0.0f), 1.0f);
        float nz = fminf(fmaxf((rec.z - b0z) / sz, 0.0f), 1.0f);
        float px = nx * (float)(GS - 1);
        float py = ny * (float)(GS - 1);
        float pz = nz * (float)(GS - 1);
        int x0 = (int)px, y0 = (int)py, z0 = (int)pz;
        int x1 = min(x0 + 1, GS - 1);
        int y1 = min(y0 + 1, GS - 1);
        int z1 = min(z0 + 1, GS - 1);
        float wx = fminf(fmaxf(px - (float)x0, 0.0f), 1.0f);
        float wy = fminf(fmaxf(py - (float)y0, 0.0f), 1.0f);
        float wz = fminf(fmaxf(pz - (float)z0, 0.0f), 1.0f);

        int lx0 = x0 - xs * 4, lx1 = x1 - xs * 4;
        int ly0 = y0 - ys * 4, ly1 = y1 - ys * 4;
        int lz0 = z0 - zq * 32, lz1 = z1 - zq * 32;

        int c000 = ((lx0 * 5 + ly0) * 33 + lz0) * 2 + half;
        int c100 = ((lx1 * 5 + ly0) * 33 + lz0) * 2 + half;
        int c010 = ((lx0 * 5 + ly1) * 33 + lz0) * 2 + half;
        int c110 = ((lx1 * 5 + ly1) * 33 + lz0) * 2 + half;
        int c001 = ((lx0 * 5 + ly0) * 33 + lz1) * 2 + half;
        int c101 = ((lx1 * 5 + ly0) * 33 + lz1) * 2 + half;
        int c011 = ((lx0 * 5 + ly1) * 33 + lz1) * 2 + half;
        int c111 = ((lx1 * 5 + ly1) * 33 + lz1) * 2 + half;

        float ux = 1.0f - wx, uy = 1.0f - wy, uz = 1.0f - wz;
        float w000 = ux*uy*uz, w100 = wx*uy*uz, w010 = ux*wy*uz, w110 = wx*wy*uz;
        float w001 = ux*uy*wz, w101 = wx*uy*wz, w011 = ux*wy*wz, w111 = wx*wy*wz;

        float4 A = tile[c000], B = tile[c100], C = tile[c010], D = tile[c110];
        float4 E = tile[c001], F = tile[c101], H = tile[c011], Kk = tile[c111];

        f32x4 o;
        o.x = A.x*w000 + B.x*w100 + C.x*w010 + D.x*w110 + E.x*w001 + F.x*w101 + H.x*w011 + Kk.x*w111;
        o.y = A.y*w000 + B.y*w100 + C.y*w010 + D.y*w110 + E.y*w001 + F.y*w101 + H.y*w011 + Kk.y*w111;
        o.z = A.z*w000 + B.z*w100 + C.z*w010 + D.z*w110 + E.z*w001 + F.z*w101 + H.z*w011 + Kk.z*w111;
        o.w = A.w*w000 + B.w*w100 + C.w*w010 + D.w*w110 + E.w*w001 + F.w*w101 + H.w*w011 + Kk.w*w111;

        // NON-TEMPORAL scattered store (nt flag): write-once data, bypass
        // L2 line retention. Pair lanes still cover contiguous 32B.
        __builtin_nontemporal_store(o, (f32x4*)(out4 + ((long long)orig * 2 + half)));
    }
}

// ---------------- fallback: direct (round-1) kernel ----------------
__global__ __launch_bounds__(256) void trilerp_direct(
    const float* __restrict__ coords,
    const float* __restrict__ grid,
    const float* __restrict__ bbox_min,
    const float* __restrict__ bbox_max,
    float* __restrict__ out, int n)
{
    int i = blockIdx.x * blockDim.x + threadIdx.x;
    if (i >= n) return;
    const float eps = 1e-6f;
    float b0x = bbox_min[0], b0y = bbox_min[1], b0z = bbox_min[2];
    float sx = fmaxf(bbox_max[0] - b0x, eps);
    float sy = fmaxf(bbox_max[1] - b0y, eps);
    float sz = fmaxf(bbox_max[2] - b0z, eps);
    float nx = fminf(fmaxf((coords[3*i] - b0x) / sx, 0.0f), 1.0f);
    float ny = fminf(fmaxf((coords[3*i+1] - b0y) / sy, 0.0f), 1.0f);
    float nz = fminf(fmaxf((coords[3*i+2] - b0z) / sz, 0.0f), 1.0f);
    float px = nx * (float)(GS - 1), py = ny * (float)(GS - 1), pz = nz * (float)(GS - 1);
    int x0 = (int)px, y0 = (int)py, z0 = (int)pz;
    int x1 = min(x0 + 1, GS - 1), y1 = min(y0 + 1, GS - 1), z1 = min(z0 + 1, GS - 1);
    float wx = fminf(fmaxf(px - (float)x0, 0.0f), 1.0f);
    float wy = fminf(fmaxf(py - (float)y0, 0.0f), 1.0f);
    float wz = fminf(fmaxf(pz - (float)z0, 0.0f), 1.0f);
    float ux = 1.0f - wx, uy = 1.0f - wy, uz = 1.0f - wz;
    float w000 = ux*uy*uz, w100 = wx*uy*uz, w010 = ux*wy*uz, w110 = wx*wy*uz;
    float w001 = ux*uy*wz, w101 = wx*uy*wz, w011 = ux*wy*wz, w111 = wx*wy*wz;
    const float4* g4 = (const float4*)grid;
    int bx0 = x0 * GS, bx1 = x1 * GS;
    int p000 = ((bx0 + y0) * GS + z0) * 2, p100 = ((bx1 + y0) * GS + z0) * 2;
    int p010 = ((bx0 + y1) * GS + z0) * 2, p110 = ((bx1 + y1) * GS + z0) * 2;
    int p001 = ((bx0 + y0) * GS + z1) * 2, p101 = ((bx1 + y0) * GS + z1) * 2;
    int p011 = ((bx0 + y1) * GS + z1) * 2, p111 = ((bx1 + y1) * GS + z1) * 2;
    float4 a0 = g4[p000], a1 = g4[p000+1], b0 = g4[p100], b1 = g4[p100+1];
    float4 c0 = g4[p010], c1 = g4[p010+1], d0 = g4[p110], d1 = g4[p110+1];
    float4 e0 = g4[p001], e1 = g4[p001+1], f0 = g4[p101], f1 = g4[p101+1];
    float4 h0 = g4[p011], h1 = g4[p011+1], k0 = g4[p111], k1 = g4[p111+1];
    float4 o0, o1;
    o0.x = a0.x*w000 + b0.x*w100 + c0.x*w010 + d0.x*w110 + e0.x*w001 + f0.x*w101 + h0.x*w011 + k0.x*w111;
    o0.y = a0.y*w000 + b0.y*w100 + c0.y*w010 + d0.y*w110 + e0.y*w001 + f0.y*w101 + h0.y*w011 + k0.y*w111;
    o0.z = a0.z*w000 + b0.z*w100 + c0.z*w010 + d0.z*w110 + e0.z*w001 + f0.z*w101 + h0.z*w011 + k0.z*w111;
    o0.w = a0.w*w000 + b0.w*w100 + c0.w*w010 + d0.w*w110 + e0.w*w001 + f0.w*w101 + h0.w*w011 + k0.w*w111;
    o1.x = a1.x*w000 + b1.x*w100 + c1.x*w010 + d1.x*w110 + e1.x*w001 + f1.x*w101 + h1.x*w011 + k1.x*w111;
    o1.y = a1.y*w000 + b1.y*w100 + c1.y*w010 + d1.y*w110 + e1.y*w001 + f1.y*w101 + h1.y*w011 + k1.y*w111;
    o1.z = a1.z*w000 + b1.z*w100 + c1.z*w010 + d1.z*w110 + e1.z*w001 + f1.z*w101 + h1.z*w011 + k1.z*w111;
    o1.w = a1.w*w000 + b1.w*w100 + c1.w*w010 + d1.w*w110 + e1.w*w001 + f1.w*w101 + h1.w*w011 + k1.w*w111;
    float4* outp = (float4*)out;
    outp[(long long)i * 2 + 0] = o0;
    outp[(long long)i * 2 + 1] = o1;
}

extern "C" void kernel_launch(void* const* d_in, const int* in_sizes, int n_in,
                              void* d_out, int out_size, void* d_ws, size_t ws_size,
                              hipStream_t stream) {
    const float* coords   = (const float*)d_in[0];
    const float* grid     = (const float*)d_in[1];
    const float* bbox_min = (const float*)d_in[2];
    const float* bbox_max = (const float*)d_in[3];
    float* out = (float*)d_out;

    int n = in_sizes[0] / 3;

    // ws: [cursor32 128B][cursor4096 16KB @256][recs1 @32768][recs2]
    size_t cur32_off = 0;
    size_t cur2_off  = 256;
    size_t recs1_off = 32768;
    size_t recs2_off = recs1_off + (size_t)NBX * CAP1 * 16;   // +33.6 MB
    size_t needed    = recs2_off + (size_t)NB2 * CAP2 * 16;   // +46.1 MB ~= 80 MB

    int nb_sort = (n + K_PTS - 1) / K_PTS;
    int nb_dir  = (n + 255) / 256;

    if (ws_size >= needed) {
        unsigned* cur32 = (unsigned*)((char*)d_ws + cur32_off);
        unsigned* cur2  = (unsigned*)((char*)d_ws + cur2_off);
        float4*   recs1 = (float4*)((char*)d_ws + recs1_off);
        float4*   recs2 = (float4*)((char*)d_ws + recs2_off);

        k_init    <<<16, 256, 0, stream>>>(cur32, cur2);
        k_scatter1<<<nb_sort, 256, 0, stream>>>(coords, bbox_min, bbox_max, cur32, recs1, n);
        k_scatter2<<<NBX * 64, 256, 0, stream>>>(recs1, bbox_min, bbox_max, cur32, cur2, recs2);
        k_interp_staged<<<NB2, 512, 0, stream>>>(recs2, cur2, grid, bbox_min, bbox_max,
                                                 (float4*)out);
    } else {
        trilerp_direct<<<nb_dir, 256, 0, stream>>>(coords, grid, bbox_min, bbox_max, out, n);
    }
}